// Round 1
// baseline (423.176 us; speedup 1.0000x reference)
//
#include <hip/hip_runtime.h>
#include <math.h>

// RandomActivation: out[r][c] = min(act(func_id[c], x[r][c]), max_output[c])
// BATCH=16384, DIM=4096, fp32 in/out. Memory-bound: ~537 MB traffic, floor ~85us.

#define RA_DIM 4096
#define RA_DIM4 (RA_DIM / 4)  // 1024, power of two

__device__ __forceinline__ float ra_act(float v, int f) {
    // sigmoid shared by silu (f==1) and sigmoid (f==3)
    float sig = 1.0f / (1.0f + __expf(-v));
    float r;
    if (f == 0)       r = fmaxf(v, 0.0f);          // relu
    else if (f == 1)  r = v * sig;                  // silu
    else if (f == 2)  r = (v >= 0.0f) ? v : 0.01f * v; // leaky_relu
    else if (f == 3)  r = sig;                      // sigmoid
    else              r = tanhf(v);                 // tanh (libm: safe at large |v|)
    return r;
}

__global__ __launch_bounds__(256) void RandomActivation_24567212933826_kernel(
        const float4* __restrict__ x4,
        const float4* __restrict__ mo4,   // max_output, [DIM4]
        const int4*   __restrict__ fid4,  // func_id,    [DIM4]
        float4* __restrict__ out4,
        long long total4) {
    long long i = (long long)blockIdx.x * blockDim.x + threadIdx.x;
    if (i >= total4) return;
    int c4 = (int)(i & (RA_DIM4 - 1));  // column/4 index (row-major, DIM multiple of 4)

    float4 xv = x4[i];
    int4   f  = fid4[c4];
    float4 m  = mo4[c4];

    float4 r;
    r.x = fminf(ra_act(xv.x, f.x), m.x);
    r.y = fminf(ra_act(xv.y, f.y), m.y);
    r.z = fminf(ra_act(xv.z, f.z), m.z);
    r.w = fminf(ra_act(xv.w, f.w), m.w);

    out4[i] = r;
}

extern "C" void kernel_launch(void* const* d_in, const int* in_sizes, int n_in,
                              void* d_out, int out_size, void* d_ws, size_t ws_size,
                              hipStream_t stream) {
    const float4* x4   = (const float4*)d_in[0];   // x [BATCH, DIM] fp32
    const float4* mo4  = (const float4*)d_in[1];   // max_output [DIM] fp32
    const int4*   fid4 = (const int4*)d_in[2];     // func_id [DIM] int32
    float4*       out4 = (float4*)d_out;

    long long total  = (long long)in_sizes[0];     // BATCH*DIM
    long long total4 = total / 4;

    const int block = 256;
    long long grid = (total4 + block - 1) / block; // 65536 for 16384x4096

    RandomActivation_24567212933826_kernel<<<(dim3)(unsigned)grid, block, 0, stream>>>(
        x4, mo4, fid4, out4, total4);
}